// Round 5
// baseline (159.129 us; speedup 1.0000x reference)
//
#include <hip/hip_runtime.h>
#include <math.h>

// ---------------------------------------------------------------------------
// TwoSimplicialAttention, MI355X. Structure exploit: mask kills attention for
// all s < 2016; only last 32 rows/batch (64 rows) carry attention. Everything
// else is out = LayerNorm(x).
//
// R4b: atomic Y/delta (R2 structure); proj ksplit=32 (2048 blocks, 8/CU);
// attn: no V staging (direct global->reg), swizzled K/Kp, float4 P,
// 512 x 128-thread blocks; ln: non-temporal stores (native vec type).
// ---------------------------------------------------------------------------

typedef float nfloat4 __attribute__((ext_vector_type(4)));

// workspace layout (floats) -- single accumulated buffers
#define YQ_OFF    0         // 64 x 1024
#define YK_OFF    65536
#define YKP_OFF   131072
#define YV_OFF    196608
#define Z_OFF     262144    // 64 x 1024
#define DELTA_OFF 327680    // 64 x 1024
#define WS_FLOATS 393216    // 1.5 MB

__global__ __launch_bounds__(256) void zero_ws(float4* __restrict__ ws) {
  ws[blockIdx.x * 256 + threadIdx.x] = make_float4(0.f, 0.f, 0.f, 0.f);
}

__device__ __forceinline__ int sw_idx(int row, int d) {
  // XOR-swizzled index for 32x64 tiles read as float4 along d by row-groups
  return row * 64 + ((((d >> 2) + (row >> 2)) & 15) << 2) + (d & 3);
}

// ---- kernel A: Y[64][4096] += x_win @ [W_Q|W_K|W_Kp|W_V] (32-k chunks) ----
// grid (64 = 4z x 16colblk, 32 ksplit) = 2048 blocks, 8/CU. lane=row,
// wave owns 16 cols, W rows via scalar cache (s_load_dwordx16).
__global__ __launch_bounds__(256, 4) void proj_kernel(
    const float* __restrict__ x,
    const float* __restrict__ Wq, const float* __restrict__ Wk,
    const float* __restrict__ Wkp, const float* __restrict__ Wv,
    float* __restrict__ Y) {
  __shared__ float xs[64 * 65];      // staging [32k][64r]; epilogue [64][65]
  const int tid = threadIdx.x;
  const int z    = blockIdx.x >> 4;
  const int col0 = (blockIdx.x & 15) * 64;
  const int k0   = blockIdx.y * 32;
  const float* __restrict__ W =
      (z == 0) ? Wq : ((z == 1) ? Wk : ((z == 2) ? Wkp : Wv));

  // stage x^T tile: 64 rows x 32 k (coalesced float4)
  #pragma unroll
  for (int i = 0; i < 2; i++) {
    int e = i * 256 + tid;           // 512 slots: r(64) x quad(8)
    int r = e >> 3, q = e & 7;
    int b = r >> 5, t = r & 31;
    float4 v = *(const float4*)(x + ((b * 2048 + 2016 + t) * 1024 + k0 + q * 4));
    xs[(q * 4 + 0) * 65 + r] = v.x;
    xs[(q * 4 + 1) * 65 + r] = v.y;
    xs[(q * 4 + 2) * 65 + r] = v.z;
    xs[(q * 4 + 3) * 65 + r] = v.w;
  }
  __syncthreads();

  const int wave = __builtin_amdgcn_readfirstlane(tid >> 6);  // uniform
  const int lane = tid & 63;                                   // = row
  const float* __restrict__ Wt = W + (size_t)k0 * 1024 + col0 + wave * 16;

  float acc[16];
  #pragma unroll
  for (int c = 0; c < 16; c++) acc[c] = 0.f;

  #pragma unroll 4
  for (int kk = 0; kk < 32; kk++) {
    float xv = xs[kk * 65 + lane];               // conflict-free vector read
    const float* __restrict__ wrow = Wt + kk * 1024;  // uniform -> s_load x16
    #pragma unroll
    for (int c = 0; c < 16; c++) acc[c] = fmaf(xv, wrow[c], acc[c]);
  }

  // transpose through LDS for coalesced atomics
  __syncthreads();
  #pragma unroll
  for (int c = 0; c < 16; c++) xs[lane * 65 + wave * 16 + c] = acc[c];
  __syncthreads();
  float* __restrict__ Yo = Y + z * 65536 + col0;
  #pragma unroll
  for (int i = 0; i < 16; i++) {
    int r = wave * 16 + i;
    atomicAdd(Yo + r * 1024 + lane, xs[r * 65 + lane]);  // coalesced
  }
}

// ---- kernel B: attention for the 64 window rows ---------------------------
// grid (16 s-groups, 16 heads, 2 batches) = 512 blocks, 128 thr (2 waves),
// one (b,h,s) per wave. V column loaded direct global->reg (no LDS).
__global__ __launch_bounds__(128) void attn_kernel(
    const float* __restrict__ Y, float* __restrict__ Zout) {
  __shared__ float Kn[32 * 64], Kp[32 * 64];     // swizzled
  __shared__ float Pt[2][32 * 36];               // [k][j] pad 36
  __shared__ float qs[2][64];
  const int tid = threadIdx.x;
  const int wave = tid >> 6, lane = tid & 63;
  const int h = blockIdx.y, b = blockIdx.z;
  const int m = blockIdx.x * 2 + wave;   // s_local; valid j,k <= m
  const int r = b * 32 + m;

  // V column direct to regs (independent loads, issue early, coalesced)
  float vreg[32];
  #pragma unroll
  for (int k = 0; k < 32; k++)
    vreg[k] = Y[YV_OFF + (b * 32 + k) * 1024 + h * 64 + lane];

  // q (lane = d)
  float q = Y[YQ_OFF + r * 1024 + h * 64 + lane];

  // stage K / Kp tiles (swizzled)
  #pragma unroll
  for (int i = 0; i < 16; i++) {
    int e = i * 128 + tid;             // 2048: row(32) x d(64)
    int row = e >> 6, d = e & 63;
    int src = (b * 32 + row) * 1024 + h * 64 + d;
    Kn[sw_idx(row, d)] = Y[YK_OFF + src];
    Kp[sw_idx(row, d)] = Y[YKP_OFF + src];
  }
  __syncthreads();

  // l2-normalize K, Kp rows (wave w: rows 16w..16w+15; lane = d)
  for (int rr = 0; rr < 16; rr++) {
    int row = wave * 16 + rr;
    int a = sw_idx(row, lane);
    float kv = Kn[a];
    float s2 = kv * kv;
    #pragma unroll
    for (int off = 1; off < 64; off <<= 1) s2 += __shfl_xor(s2, off);
    Kn[a] = kv * (1.f / (sqrtf(s2) + 1e-7f));
    float pv = Kp[a];
    float p2 = pv * pv;
    #pragma unroll
    for (int off = 1; off < 64; off <<= 1) p2 += __shfl_xor(p2, off);
    Kp[a] = pv * (1.f / (sqrtf(p2) + 1e-7f));
  }

  // q-hat
  float q2 = q * q;
  #pragma unroll
  for (int off = 1; off < 64; off <<= 1) q2 += __shfl_xor(q2, off);
  q *= (1.f / (sqrtf(q2) + 1e-7f));
  qs[wave][lane] = q;
  __syncthreads();

  // A[j][k] = sum_d qhat[d] Khat[j][d] Kphat[k][d]; 4x4 tile per lane
  const int lj = lane >> 3, lk = lane & 7;
  float acc[4][4];
  #pragma unroll
  for (int a = 0; a < 4; a++)
    #pragma unroll
    for (int c = 0; c < 4; c++) acc[a][c] = 0.f;

  const float* qw = qs[wave];
  for (int dq = 0; dq < 16; dq++) {
    float4 q4 = *(const float4*)(qw + dq * 4);   // broadcast
    const int cj = (((dq + lj) & 15) << 2);      // swizzled quad offset
    const int ck = (((dq + lk) & 15) << 2);
    float4 t4[4], kp4[4];
    #pragma unroll
    for (int tj = 0; tj < 4; tj++) {
      float4 kv = *(const float4*)(Kn + (lj * 4 + tj) * 64 + cj);
      t4[tj].x = q4.x * kv.x; t4[tj].y = q4.y * kv.y;
      t4[tj].z = q4.z * kv.z; t4[tj].w = q4.w * kv.w;
    }
    #pragma unroll
    for (int tk = 0; tk < 4; tk++)
      kp4[tk] = *(const float4*)(Kp + (lk * 4 + tk) * 64 + ck);
    #pragma unroll
    for (int tj = 0; tj < 4; tj++)
      #pragma unroll
      for (int tk = 0; tk < 4; tk++)
        acc[tj][tk] += t4[tj].x * kp4[tk].x + t4[tj].y * kp4[tk].y
                     + t4[tj].z * kp4[tk].z + t4[tj].w * kp4[tk].w;
  }

  // masked softmax (scale 1/sqrt(64) = 0.125)
  float amax = -1e30f;
  #pragma unroll
  for (int tj = 0; tj < 4; tj++)
    #pragma unroll
    for (int tk = 0; tk < 4; tk++) {
      int j = lj * 4 + tj, k = lk * 4 + tk;
      if (j <= m && k <= m) amax = fmaxf(amax, acc[tj][tk] * 0.125f);
    }
  #pragma unroll
  for (int off = 1; off < 64; off <<= 1) amax = fmaxf(amax, __shfl_xor(amax, off));

  float lsum = 0.f;
  float* ptw = Pt[wave];
  #pragma unroll
  for (int tk = 0; tk < 4; tk++) {
    int k = lk * 4 + tk;
    float4 ev;
    float* e = (float*)&ev;
    #pragma unroll
    for (int tj = 0; tj < 4; tj++) {
      int j = lj * 4 + tj;
      float xv = 0.f;
      if (j <= m && k <= m) xv = __expf(acc[tj][tk] * 0.125f - amax);
      e[tj] = xv;
      lsum += xv;
    }
    *(float4*)(ptw + k * 36 + lj * 4) = ev;      // b128
  }
  #pragma unroll
  for (int off = 1; off < 64; off <<= 1) lsum += __shfl_xor(lsum, off);
  float inv = 1.f / lsum;
  __builtin_amdgcn_wave_barrier();

  // Z[d] = sum_k V[k][d] * (sum_j P[j][k] V[j][d]); lane = d
  float zacc = 0.f;
  for (int k = 0; k <= m; k++) {
    float g0 = 0.f, g1 = 0.f, g2 = 0.f, g3 = 0.f;
    #pragma unroll
    for (int jq = 0; jq < 8; jq++) {
      float4 p = *(const float4*)(ptw + k * 36 + jq * 4);  // b128 broadcast
      g0 = fmaf(p.x, vreg[jq * 4 + 0], g0);
      g1 = fmaf(p.y, vreg[jq * 4 + 1], g1);
      g2 = fmaf(p.z, vreg[jq * 4 + 2], g2);
      g3 = fmaf(p.w, vreg[jq * 4 + 3], g3);
    }
    zacc = fmaf((g0 + g1) + (g2 + g3), vreg[k], zacc);
  }
  Zout[r * 1024 + h * 64 + lane] = zacc * inv;
}

// ---- kernel C: delta[64][1024] += Z @ W_O (32-k chunks) -------------------
// grid (16 colblk, 32 ksplit) = 512 blocks, 2/CU.
__global__ __launch_bounds__(256, 4) void wo_kernel(
    const float* __restrict__ Zr, const float* __restrict__ Wo,
    float* __restrict__ delta) {
  __shared__ float xs[64 * 65];
  const int tid = threadIdx.x;
  const int col0 = blockIdx.x * 64;
  const int k0   = blockIdx.y * 32;

  #pragma unroll
  for (int i = 0; i < 2; i++) {
    int e = i * 256 + tid;           // 512 slots: r(64) x quad(8)
    int r = e >> 3, q = e & 7;
    float4 v = *(const float4*)(Zr + r * 1024 + k0 + q * 4);
    xs[(q * 4 + 0) * 65 + r] = v.x;
    xs[(q * 4 + 1) * 65 + r] = v.y;
    xs[(q * 4 + 2) * 65 + r] = v.z;
    xs[(q * 4 + 3) * 65 + r] = v.w;
  }
  __syncthreads();

  const int wave = __builtin_amdgcn_readfirstlane(tid >> 6);
  const int lane = tid & 63;         // = row
  const float* __restrict__ Wt = Wo + (size_t)k0 * 1024 + col0 + wave * 16;

  float acc[16];
  #pragma unroll
  for (int c = 0; c < 16; c++) acc[c] = 0.f;

  #pragma unroll 4
  for (int kk = 0; kk < 32; kk++) {
    float xv = xs[kk * 65 + lane];
    const float* __restrict__ wrow = Wt + kk * 1024;
    #pragma unroll
    for (int c = 0; c < 16; c++) acc[c] = fmaf(xv, wrow[c], acc[c]);
  }

  __syncthreads();
  #pragma unroll
  for (int c = 0; c < 16; c++) xs[lane * 65 + wave * 16 + c] = acc[c];
  __syncthreads();
  #pragma unroll
  for (int i = 0; i < 16; i++) {
    int r = wave * 16 + i;
    atomicAdd(delta + r * 1024 + col0 + lane, xs[r * 65 + lane]);
  }
}

// ---- kernel D: out = LayerNorm(x + delta), one wave per row, NT stores ----
__global__ __launch_bounds__(256, 4) void ln_kernel(
    const float4* __restrict__ x4, const float4* __restrict__ delta4,
    const float4* __restrict__ g4, const float4* __restrict__ b4,
    float4* __restrict__ out4) {
  const int tid = threadIdx.x;
  const int wave = tid >> 6, lane = tid & 63;
  const int row = blockIdx.x * 4 + wave;       // 0..4095
  const int b = row >> 11, s = row & 2047;

  float4 v[4];
  #pragma unroll
  for (int i = 0; i < 4; i++) v[i] = x4[row * 256 + i * 64 + lane];
  if (s >= 2016) {                             // wave-uniform branch
    int drow = b * 32 + (s - 2016);
    #pragma unroll
    for (int i = 0; i < 4; i++) {
      float4 d = delta4[drow * 256 + i * 64 + lane];
      v[i].x += d.x; v[i].y += d.y; v[i].z += d.z; v[i].w += d.w;
    }
  }
  float sum = 0.f, ss = 0.f;
  #pragma unroll
  for (int i = 0; i < 4; i++) {
    sum += v[i].x + v[i].y + v[i].z + v[i].w;
    ss  += v[i].x * v[i].x + v[i].y * v[i].y + v[i].z * v[i].z + v[i].w * v[i].w;
  }
  #pragma unroll
  for (int off = 1; off < 64; off <<= 1) {
    sum += __shfl_xor(sum, off);
    ss  += __shfl_xor(ss, off);
  }
  float mu   = sum * (1.f / 1024.f);
  float var  = ss * (1.f / 1024.f) - mu * mu;
  float rstd = rsqrtf(var + 1e-5f);

  #pragma unroll
  for (int i = 0; i < 4; i++) {
    float4 g = g4[i * 64 + lane];
    float4 be = b4[i * 64 + lane];
    nfloat4 o;
    o.x = (v[i].x - mu) * rstd * g.x + be.x;
    o.y = (v[i].y - mu) * rstd * g.y + be.y;
    o.z = (v[i].z - mu) * rstd * g.z + be.z;
    o.w = (v[i].w - mu) * rstd * g.w + be.w;
    __builtin_nontemporal_store(o, (nfloat4*)&out4[row * 256 + i * 64 + lane]);
  }
}

// ---------------------------------------------------------------------------
extern "C" void kernel_launch(void* const* d_in, const int* in_sizes, int n_in,
                              void* d_out, int out_size, void* d_ws, size_t ws_size,
                              hipStream_t stream) {
  const float* x   = (const float*)d_in[0];
  const float* Wq  = (const float*)d_in[1];
  const float* Wk  = (const float*)d_in[2];
  const float* Wv  = (const float*)d_in[3];  // NB: dict order, W_V before W_Kp
  const float* Wkp = (const float*)d_in[4];
  const float* Wo  = (const float*)d_in[5];
  const float* gam = (const float*)d_in[6];
  const float* bet = (const float*)d_in[7];
  float* out = (float*)d_out;
  float* ws  = (float*)d_ws;   // needs 1.5 MB

  hipLaunchKernelGGL(zero_ws, dim3(WS_FLOATS / 1024), dim3(256), 0, stream,
                     (float4*)ws);
  hipLaunchKernelGGL(proj_kernel, dim3(64, 32), dim3(256), 0, stream,
                     x, Wq, Wk, Wkp, Wv, ws);
  hipLaunchKernelGGL(attn_kernel, dim3(16, 16, 2), dim3(128), 0, stream,
                     ws, ws + Z_OFF);
  hipLaunchKernelGGL(wo_kernel, dim3(16, 32), dim3(256), 0, stream,
                     ws + Z_OFF, Wo, ws + DELTA_OFF);
  hipLaunchKernelGGL(ln_kernel, dim3(1024), dim3(256), 0, stream,
                     (const float4*)x, (const float4*)(ws + DELTA_OFF),
                     (const float4*)gam, (const float4*)bet, (float4*)out);
}

// Round 6
// 148.627 us; speedup vs baseline: 1.0707x; 1.0707x over previous
//
#include <hip/hip_runtime.h>
#include <math.h>

// ---------------------------------------------------------------------------
// TwoSimplicialAttention, MI355X. Structure exploit: mask kills attention for
// all s < 2016; only last 32 rows/batch (64 rows) carry attention. Everything
// else is out = LayerNorm(x).
//
// R6: ZERO atomics. proj -> 16 split-k partials (plain stores) -> reduce
// kernel -> Y. wo -> 16 partials; ln sums them in the window branch.
// attn keeps the swizzled 128-thread form. No zero_ws.
// ---------------------------------------------------------------------------

// workspace layout (floats)
#define NS        16
#define YPART_OFF 0                       // 16 x 262144 (each 64x4096)
#define YFULL_OFF 4194304                 // 262144: Q|K|Kp|V each 64x1024
#define Z_OFF     4456448                 // 65536
#define DPART_OFF 4521984                 // 16 x 65536
// total 5570560 floats = 22.3 MB

// offsets inside YFULL
#define YQ_OFF    0
#define YK_OFF    65536
#define YKP_OFF   131072
#define YV_OFF    196608

__device__ __forceinline__ int sw_idx(int row, int d) {
  // XOR-swizzled index for 32x64 tiles read as float4 along d by row-groups
  return row * 64 + ((((d >> 2) + (row >> 2)) & 15) << 2) + (d & 3);
}

// ---- kernel A: Ypart[ks] = x_win(64 x 64k-chunk) @ W-chunk ----------------
// grid (64 = 4z x 16colblk, 16 ksplit) = 1024 blocks (R2 shape). lane=row,
// wave owns 16 cols, W rows via scalar cache (s_load_dwordx16). Plain stores.
__global__ __launch_bounds__(256, 4) void proj_kernel(
    const float* __restrict__ x,
    const float* __restrict__ Wq, const float* __restrict__ Wk,
    const float* __restrict__ Wkp, const float* __restrict__ Wv,
    float* __restrict__ ws) {
  __shared__ float xs[64 * 65];      // [kk][r]
  const int tid = threadIdx.x;
  const int z    = blockIdx.x >> 4;
  const int col0 = (blockIdx.x & 15) * 64;
  const int ks   = blockIdx.y;
  const int k0   = ks * 64;
  const float* __restrict__ W =
      (z == 0) ? Wq : ((z == 1) ? Wk : ((z == 2) ? Wkp : Wv));

  // stage x^T tile: 64 rows x 64 k (coalesced float4)
  #pragma unroll
  for (int i = 0; i < 4; i++) {
    int e = i * 256 + tid;           // 1024 slots: r(64) x quad(16)
    int r = e >> 4, q = e & 15;
    int b = r >> 5, t = r & 31;
    float4 v = *(const float4*)(x + ((b * 2048 + 2016 + t) * 1024 + k0 + q * 4));
    xs[(q * 4 + 0) * 65 + r] = v.x;
    xs[(q * 4 + 1) * 65 + r] = v.y;
    xs[(q * 4 + 2) * 65 + r] = v.z;
    xs[(q * 4 + 3) * 65 + r] = v.w;
  }
  __syncthreads();

  const int wave = __builtin_amdgcn_readfirstlane(tid >> 6);  // uniform
  const int lane = tid & 63;                                   // = row
  const float* __restrict__ Wt = W + (size_t)k0 * 1024 + col0 + wave * 16;

  float acc[16];
  #pragma unroll
  for (int c = 0; c < 16; c++) acc[c] = 0.f;

  #pragma unroll 4
  for (int kk = 0; kk < 64; kk++) {
    float xv = xs[kk * 65 + lane];               // conflict-free vector read
    const float* __restrict__ wrow = Wt + kk * 1024;  // uniform -> s_load x16
    #pragma unroll
    for (int c = 0; c < 16; c++) acc[c] = fmaf(xv, wrow[c], acc[c]);
  }

  // transpose through LDS for coalesced plain stores
  __syncthreads();
  #pragma unroll
  for (int c = 0; c < 16; c++) xs[lane * 65 + wave * 16 + c] = acc[c];
  __syncthreads();
  float* __restrict__ Yo = ws + (size_t)YPART_OFF + (size_t)ks * 262144
                         + z * 65536 + col0;
  #pragma unroll
  for (int i = 0; i < 16; i++) {
    int r = wave * 16 + i;
    Yo[r * 1024 + lane] = xs[r * 65 + lane];     // coalesced store
  }
}

// ---- kernel A2: Y = sum of 16 partials (float4, fully coalesced) ----------
__global__ __launch_bounds__(256) void reduce_kernel(
    const float4* __restrict__ parts, float4* __restrict__ out) {
  const int i = blockIdx.x * 256 + threadIdx.x;  // 65536 float4 outputs
  float4 a = parts[i];
  #pragma unroll
  for (int s = 1; s < NS; s++) {
    float4 p = parts[(size_t)s * 65536 + i];
    a.x += p.x; a.y += p.y; a.z += p.z; a.w += p.w;
  }
  out[i] = a;
}

// ---- kernel B: attention for the 64 window rows ---------------------------
// grid (16 s-groups, 16 heads, 2 batches) = 512 blocks, 128 thr (2 waves),
// one (b,h,s) per wave. V column direct global->reg.
__global__ __launch_bounds__(128) void attn_kernel(
    const float* __restrict__ Y, float* __restrict__ Zout) {
  __shared__ float Kn[32 * 64], Kp[32 * 64];     // swizzled
  __shared__ float Pt[2][32 * 36];               // [k][j] pad 36
  __shared__ float qs[2][64];
  const int tid = threadIdx.x;
  const int wave = tid >> 6, lane = tid & 63;
  const int h = blockIdx.y, b = blockIdx.z;
  const int m = blockIdx.x * 2 + wave;   // s_local; valid j,k <= m
  const int r = b * 32 + m;

  // V column direct to regs (independent loads, issue early, coalesced)
  float vreg[32];
  #pragma unroll
  for (int k = 0; k < 32; k++)
    vreg[k] = Y[YV_OFF + (b * 32 + k) * 1024 + h * 64 + lane];

  // q (lane = d)
  float q = Y[YQ_OFF + r * 1024 + h * 64 + lane];

  // stage K / Kp tiles (swizzled)
  #pragma unroll
  for (int i = 0; i < 16; i++) {
    int e = i * 128 + tid;             // 2048: row(32) x d(64)
    int row = e >> 6, d = e & 63;
    int src = (b * 32 + row) * 1024 + h * 64 + d;
    Kn[sw_idx(row, d)] = Y[YK_OFF + src];
    Kp[sw_idx(row, d)] = Y[YKP_OFF + src];
  }
  __syncthreads();

  // l2-normalize K, Kp rows (wave w: rows 16w..16w+15; lane = d)
  for (int rr = 0; rr < 16; rr++) {
    int row = wave * 16 + rr;
    int a = sw_idx(row, lane);
    float kv = Kn[a];
    float s2 = kv * kv;
    #pragma unroll
    for (int off = 1; off < 64; off <<= 1) s2 += __shfl_xor(s2, off);
    Kn[a] = kv * (1.f / (sqrtf(s2) + 1e-7f));
    float pv = Kp[a];
    float p2 = pv * pv;
    #pragma unroll
    for (int off = 1; off < 64; off <<= 1) p2 += __shfl_xor(p2, off);
    Kp[a] = pv * (1.f / (sqrtf(p2) + 1e-7f));
  }

  // q-hat
  float q2 = q * q;
  #pragma unroll
  for (int off = 1; off < 64; off <<= 1) q2 += __shfl_xor(q2, off);
  q *= (1.f / (sqrtf(q2) + 1e-7f));
  qs[wave][lane] = q;
  __syncthreads();

  // A[j][k] = sum_d qhat[d] Khat[j][d] Kphat[k][d]; 4x4 tile per lane
  const int lj = lane >> 3, lk = lane & 7;
  float acc[4][4];
  #pragma unroll
  for (int a = 0; a < 4; a++)
    #pragma unroll
    for (int c = 0; c < 4; c++) acc[a][c] = 0.f;

  const float* qw = qs[wave];
  for (int dq = 0; dq < 16; dq++) {
    float4 q4 = *(const float4*)(qw + dq * 4);   // broadcast
    const int cj = (((dq + lj) & 15) << 2);      // swizzled quad offset
    const int ck = (((dq + lk) & 15) << 2);
    float4 t4[4], kp4[4];
    #pragma unroll
    for (int tj = 0; tj < 4; tj++) {
      float4 kv = *(const float4*)(Kn + (lj * 4 + tj) * 64 + cj);
      t4[tj].x = q4.x * kv.x; t4[tj].y = q4.y * kv.y;
      t4[tj].z = q4.z * kv.z; t4[tj].w = q4.w * kv.w;
    }
    #pragma unroll
    for (int tk = 0; tk < 4; tk++)
      kp4[tk] = *(const float4*)(Kp + (lk * 4 + tk) * 64 + ck);
    #pragma unroll
    for (int tj = 0; tj < 4; tj++)
      #pragma unroll
      for (int tk = 0; tk < 4; tk++)
        acc[tj][tk] += t4[tj].x * kp4[tk].x + t4[tj].y * kp4[tk].y
                     + t4[tj].z * kp4[tk].z + t4[tj].w * kp4[tk].w;
  }

  // masked softmax (scale 1/sqrt(64) = 0.125)
  float amax = -1e30f;
  #pragma unroll
  for (int tj = 0; tj < 4; tj++)
    #pragma unroll
    for (int tk = 0; tk < 4; tk++) {
      int j = lj * 4 + tj, k = lk * 4 + tk;
      if (j <= m && k <= m) amax = fmaxf(amax, acc[tj][tk] * 0.125f);
    }
  #pragma unroll
  for (int off = 1; off < 64; off <<= 1) amax = fmaxf(amax, __shfl_xor(amax, off));

  float lsum = 0.f;
  float* ptw = Pt[wave];
  #pragma unroll
  for (int tk = 0; tk < 4; tk++) {
    int k = lk * 4 + tk;
    float4 ev;
    float* e = (float*)&ev;
    #pragma unroll
    for (int tj = 0; tj < 4; tj++) {
      int j = lj * 4 + tj;
      float xv = 0.f;
      if (j <= m && k <= m) xv = __expf(acc[tj][tk] * 0.125f - amax);
      e[tj] = xv;
      lsum += xv;
    }
    *(float4*)(ptw + k * 36 + lj * 4) = ev;      // b128
  }
  #pragma unroll
  for (int off = 1; off < 64; off <<= 1) lsum += __shfl_xor(lsum, off);
  float inv = 1.f / lsum;
  __builtin_amdgcn_wave_barrier();

  // Z[d] = sum_k V[k][d] * (sum_j P[j][k] V[j][d]); lane = d
  float zacc = 0.f;
  for (int k = 0; k <= m; k++) {
    float g0 = 0.f, g1 = 0.f, g2 = 0.f, g3 = 0.f;
    #pragma unroll
    for (int jq = 0; jq < 8; jq++) {
      float4 p = *(const float4*)(ptw + k * 36 + jq * 4);  // b128 broadcast
      g0 = fmaf(p.x, vreg[jq * 4 + 0], g0);
      g1 = fmaf(p.y, vreg[jq * 4 + 1], g1);
      g2 = fmaf(p.z, vreg[jq * 4 + 2], g2);
      g3 = fmaf(p.w, vreg[jq * 4 + 3], g3);
    }
    zacc = fmaf((g0 + g1) + (g2 + g3), vreg[k], zacc);
  }
  Zout[r * 1024 + h * 64 + lane] = zacc * inv;
}

// ---- kernel C: Dpart[ks] = Z(64 x 64k-chunk) @ Wo-chunk, plain stores -----
// grid (16 colblk, 16 ksplit) = 256 blocks.
__global__ __launch_bounds__(256, 4) void wo_kernel(
    const float* __restrict__ Zr, const float* __restrict__ Wo,
    float* __restrict__ ws) {
  __shared__ float xs[64 * 65];
  const int tid = threadIdx.x;
  const int col0 = blockIdx.x * 64;
  const int ks   = blockIdx.y;
  const int k0   = ks * 64;

  #pragma unroll
  for (int i = 0; i < 4; i++) {
    int e = i * 256 + tid;           // 1024 slots: r(64) x quad(16)
    int r = e >> 4, q = e & 15;
    float4 v = *(const float4*)(Zr + r * 1024 + k0 + q * 4);
    xs[(q * 4 + 0) * 65 + r] = v.x;
    xs[(q * 4 + 1) * 65 + r] = v.y;
    xs[(q * 4 + 2) * 65 + r] = v.z;
    xs[(q * 4 + 3) * 65 + r] = v.w;
  }
  __syncthreads();

  const int wave = __builtin_amdgcn_readfirstlane(tid >> 6);
  const int lane = tid & 63;         // = row
  const float* __restrict__ Wt = Wo + (size_t)k0 * 1024 + col0 + wave * 16;

  float acc[16];
  #pragma unroll
  for (int c = 0; c < 16; c++) acc[c] = 0.f;

  #pragma unroll 4
  for (int kk = 0; kk < 64; kk++) {
    float xv = xs[kk * 65 + lane];
    const float* __restrict__ wrow = Wt + kk * 1024;
    #pragma unroll
    for (int c = 0; c < 16; c++) acc[c] = fmaf(xv, wrow[c], acc[c]);
  }

  __syncthreads();
  #pragma unroll
  for (int c = 0; c < 16; c++) xs[lane * 65 + wave * 16 + c] = acc[c];
  __syncthreads();
  float* __restrict__ Do = ws + (size_t)DPART_OFF + (size_t)ks * 65536 + col0;
  #pragma unroll
  for (int i = 0; i < 16; i++) {
    int r = wave * 16 + i;
    Do[r * 1024 + lane] = xs[r * 65 + lane];
  }
}

// ---- kernel D: out = LayerNorm(x + sum Dpart), one wave per row -----------
__global__ __launch_bounds__(256, 4) void ln_kernel(
    const float4* __restrict__ x4, const float4* __restrict__ dpart4,
    const float4* __restrict__ g4, const float4* __restrict__ b4,
    float4* __restrict__ out4) {
  const int tid = threadIdx.x;
  const int wave = tid >> 6, lane = tid & 63;
  const int row = blockIdx.x * 4 + wave;       // 0..4095
  const int b = row >> 11, s = row & 2047;

  float4 v[4];
  #pragma unroll
  for (int i = 0; i < 4; i++) v[i] = x4[row * 256 + i * 64 + lane];
  if (s >= 2016) {                             // wave-uniform branch
    int drow = b * 32 + (s - 2016);
    #pragma unroll
    for (int i = 0; i < 4; i++) {
      #pragma unroll
      for (int sp = 0; sp < NS; sp++) {
        float4 d = dpart4[sp * 16384 + drow * 256 + i * 64 + lane];
        v[i].x += d.x; v[i].y += d.y; v[i].z += d.z; v[i].w += d.w;
      }
    }
  }
  float sum = 0.f, ss = 0.f;
  #pragma unroll
  for (int i = 0; i < 4; i++) {
    sum += v[i].x + v[i].y + v[i].z + v[i].w;
    ss  += v[i].x * v[i].x + v[i].y * v[i].y + v[i].z * v[i].z + v[i].w * v[i].w;
  }
  #pragma unroll
  for (int off = 1; off < 64; off <<= 1) {
    sum += __shfl_xor(sum, off);
    ss  += __shfl_xor(ss, off);
  }
  float mu   = sum * (1.f / 1024.f);
  float var  = ss * (1.f / 1024.f) - mu * mu;
  float rstd = rsqrtf(var + 1e-5f);

  #pragma unroll
  for (int i = 0; i < 4; i++) {
    float4 g = g4[i * 64 + lane];
    float4 be = b4[i * 64 + lane];
    float4 o;
    o.x = (v[i].x - mu) * rstd * g.x + be.x;
    o.y = (v[i].y - mu) * rstd * g.y + be.y;
    o.z = (v[i].z - mu) * rstd * g.z + be.z;
    o.w = (v[i].w - mu) * rstd * g.w + be.w;
    out4[row * 256 + i * 64 + lane] = o;
  }
}

// ---------------------------------------------------------------------------
extern "C" void kernel_launch(void* const* d_in, const int* in_sizes, int n_in,
                              void* d_out, int out_size, void* d_ws, size_t ws_size,
                              hipStream_t stream) {
  const float* x   = (const float*)d_in[0];
  const float* Wq  = (const float*)d_in[1];
  const float* Wk  = (const float*)d_in[2];
  const float* Wv  = (const float*)d_in[3];  // NB: dict order, W_V before W_Kp
  const float* Wkp = (const float*)d_in[4];
  const float* Wo  = (const float*)d_in[5];
  const float* gam = (const float*)d_in[6];
  const float* bet = (const float*)d_in[7];
  float* out = (float*)d_out;
  float* ws  = (float*)d_ws;   // needs ~22.3 MB

  hipLaunchKernelGGL(proj_kernel, dim3(64, 16), dim3(256), 0, stream,
                     x, Wq, Wk, Wkp, Wv, ws);
  hipLaunchKernelGGL(reduce_kernel, dim3(256), dim3(256), 0, stream,
                     (const float4*)(ws + YPART_OFF), (float4*)(ws + YFULL_OFF));
  hipLaunchKernelGGL(attn_kernel, dim3(16, 16, 2), dim3(128), 0, stream,
                     ws + YFULL_OFF, ws + Z_OFF);
  hipLaunchKernelGGL(wo_kernel, dim3(16, 16), dim3(256), 0, stream,
                     ws + Z_OFF, Wo, ws);
  hipLaunchKernelGGL(ln_kernel, dim3(1024), dim3(256), 0, stream,
                     (const float4*)x, (const float4*)(ws + DPART_OFF),
                     (const float4*)gam, (const float4*)bet, (float4*)out);
}